// Round 5
// baseline (246.600 us; speedup 1.0000x reference)
//
#include <hip/hip_runtime.h>
#include <math.h>

// LightweightConv1dTBC: out[t,b,c] = sum_k x[t-15+k, b, c] * softmax(w[h(c),:])[k] + bias[c]
// T=2048 B=8 C=1024 H=16 K=31 P=15, R = C/H = 64 channels per head.
//
// R4: float4-wide along C (dwordx4 loads + NT dwordx4 stores, 1KiB/wave-instr).
// Softmax moved to a 1-block pre-kernel -> padded (H,32) table in d_ws; main
// kernel keeps its head's weights in per-lane VGPRs. 4x fewer waves/mem-instrs.

#define T_DIM 2048
#define B_DIM 8
#define C_DIM 1024
#define H_DIM 16
#define K_DIM 31
#define P_PAD 15
#define STRIP 16
#define WPAD 32

typedef float f32x4 __attribute__((ext_vector_type(4)));

__global__ void softmax_w_kernel(const float* __restrict__ weight,
                                 float* __restrict__ wtab) {
    const int h    = threadIdx.x >> 6;      // 16 waves, one head each
    const int lane = threadIdx.x & 63;
    float wv = (lane < K_DIM) ? weight[h * K_DIM + lane] : -1e30f;
    float m = wv;
    #pragma unroll
    for (int off = 32; off; off >>= 1) m = fmaxf(m, __shfl_xor(m, off));
    float e = (lane < K_DIM) ? expf(wv - m) : 0.f;
    float s = e;
    #pragma unroll
    for (int off = 32; off; off >>= 1) s += __shfl_xor(s, off);
    if (lane < WPAD) wtab[h * WPAD + lane] = (lane < K_DIM) ? (e / s) : 0.f;
}

template<bool CHECK>
__device__ __forceinline__ void run_strip4(const float* __restrict__ xb,
                                           float* __restrict__ ob,
                                           const float (&w)[K_DIM],
                                           const f32x4 bv, int t0)
{
    f32x4 acc[STRIP];
    #pragma unroll
    for (int i = 0; i < STRIP; ++i) acc[i] = bv;

    #pragma unroll
    for (int r = 0; r < STRIP + K_DIM - 1; ++r) {   // 46 streamed float4 rows
        const int t = t0 - P_PAD + r;
        f32x4 xv = (f32x4)(0.f);
        if (!CHECK || ((unsigned)t < (unsigned)T_DIM)) {
            xv = *reinterpret_cast<const f32x4*>(&xb[(size_t)t * (B_DIM * C_DIM)]);
        }
        #pragma unroll
        for (int i = 0; i < STRIP; ++i) {
            const int k = r - i;
            if (k >= 0 && k < K_DIM) {              // folds statically
                #pragma unroll
                for (int j = 0; j < 4; ++j)
                    acc[i][j] = fmaf(xv[j], w[k], acc[i][j]);
            }
        }
    }

    #pragma unroll
    for (int i = 0; i < STRIP; ++i) {
        __builtin_nontemporal_store(
            acc[i], reinterpret_cast<f32x4*>(&ob[(size_t)(t0 + i) * (B_DIM * C_DIM)]));
    }
}

__global__ __launch_bounds__(256, 4) void lwconv_tbc_kernel(
    const float* __restrict__ x,       // (T, B, C)
    const float* __restrict__ wtab,    // (H, 32) softmaxed, padded
    const float* __restrict__ bias,    // (C,)
    float* __restrict__ out)           // (T, B, C)
{
    const int tid = threadIdx.x;
    const int c   = tid * 4;                   // block covers all 1024 channels
    const int h   = c >> 6;
    const int b   = blockIdx.y;
    const int t0  = blockIdx.z * STRIP;

    // head weights -> per-lane VGPRs (8 float4 loads, L2-broadcast)
    float w[K_DIM];
    #pragma unroll
    for (int q = 0; q < 8; ++q) {
        const f32x4 t4 = *reinterpret_cast<const f32x4*>(&wtab[h * WPAD + q * 4]);
        #pragma unroll
        for (int j = 0; j < 4; ++j) {
            if (q * 4 + j < K_DIM) w[q * 4 + j] = t4[j];
        }
    }

    const f32x4 bv = *reinterpret_cast<const f32x4*>(&bias[c]);
    const float* xb = x + (size_t)b * C_DIM + c;
    float* ob = out + (size_t)b * C_DIM + c;

    const bool interior = (t0 >= P_PAD) && (t0 + STRIP - 1 + K_DIM - 1 - P_PAD < T_DIM);
    if (interior) run_strip4<false>(xb, ob, w, bv, t0);
    else          run_strip4<true >(xb, ob, w, bv, t0);
}

extern "C" void kernel_launch(void* const* d_in, const int* in_sizes, int n_in,
                              void* d_out, int out_size, void* d_ws, size_t ws_size,
                              hipStream_t stream) {
    const float* x      = (const float*)d_in[0];
    const float* weight = (const float*)d_in[1];
    const float* bias   = (const float*)d_in[2];
    float* out  = (float*)d_out;
    float* wtab = (float*)d_ws;                 // H*WPAD floats = 2 KiB

    softmax_w_kernel<<<1, H_DIM * 64, 0, stream>>>(weight, wtab);

    dim3 grid(1, B_DIM, T_DIM / STRIP);         // (1, 8, 128) = 1024 blocks
    dim3 block(256);
    lwconv_tbc_kernel<<<grid, block, 0, stream>>>(x, wtab, bias, out);
}

// Round 6
// 237.567 us; speedup vs baseline: 1.0380x; 1.0380x over previous
//
#include <hip/hip_runtime.h>
#include <math.h>

// LightweightConv1dTBC: out[t,b,c] = sum_k x[t-15+k, b, c] * softmax(w[h(c),:])[k] + bias[c]
// T=2048 B=8 C=1024 H=16 K=31 P=15, R = C/H = 64 channels per head.
//
// R5: dwordx4 loads + NT dwordx4 stores like R4, but STRIP=8 so acc=32 VGPRs
// (R4 spilled: 64 acc VGPRs + 31 w > 128 cap -> 652MB scratch traffic).
// Softmax computed per-block into a 2KB LDS table (no second kernel).
// 1-D grid + bijective XCD swizzle: each XCD streams one batch in z order,
// so the 30-row halo re-reads hit its local L2.

#define T_DIM 2048
#define B_DIM 8
#define C_DIM 1024
#define H_DIM 16
#define K_DIM 31
#define P_PAD 15
#define STRIP 8
#define WPAD 32
#define NWG (B_DIM * (T_DIM / STRIP))   // 2048 blocks

typedef float f32x4 __attribute__((ext_vector_type(4)));

template<bool CHECK>
__device__ __forceinline__ void run_strip4(const float* __restrict__ xb,
                                           float* __restrict__ ob,
                                           const float (&w)[K_DIM],
                                           const f32x4 bv, int t0)
{
    f32x4 acc[STRIP];
    #pragma unroll
    for (int i = 0; i < STRIP; ++i) acc[i] = bv;

    #pragma unroll
    for (int r = 0; r < STRIP + K_DIM - 1; ++r) {   // 38 streamed float4 rows
        const int t = t0 - P_PAD + r;
        f32x4 xv = (f32x4)(0.f);
        if (!CHECK || ((unsigned)t < (unsigned)T_DIM)) {
            xv = *reinterpret_cast<const f32x4*>(&xb[(size_t)t * (B_DIM * C_DIM)]);
        }
        #pragma unroll
        for (int i = 0; i < STRIP; ++i) {
            const int k = r - i;
            if (k >= 0 && k < K_DIM) {              // folds statically
                #pragma unroll
                for (int j = 0; j < 4; ++j)
                    acc[i][j] = fmaf(xv[j], w[k], acc[i][j]);
            }
        }
    }

    #pragma unroll
    for (int i = 0; i < STRIP; ++i) {
        __builtin_nontemporal_store(
            acc[i], reinterpret_cast<f32x4*>(&ob[(size_t)(t0 + i) * (B_DIM * C_DIM)]));
    }
}

__global__ __launch_bounds__(256, 4) void lwconv_tbc_kernel(
    const float* __restrict__ x,       // (T, B, C)
    const float* __restrict__ weight,  // (H, 1, K)
    const float* __restrict__ bias,    // (C,)
    float* __restrict__ out)           // (T, B, C)
{
    __shared__ float s_w[H_DIM][WPAD];  // 2 KB softmaxed weight table

    const int tid = threadIdx.x;

    // --- per-block softmax: threads 0..15 each handle one head (serial, tiny) ---
    if (tid < H_DIM) {
        float wv[K_DIM];
        float m = -1e30f;
        for (int k = 0; k < K_DIM; ++k) {
            wv[k] = weight[tid * K_DIM + k];
            m = fmaxf(m, wv[k]);
        }
        float s = 0.f;
        for (int k = 0; k < K_DIM; ++k) { wv[k] = expf(wv[k] - m); s += wv[k]; }
        const float inv = 1.f / s;
        for (int k = 0; k < K_DIM; ++k) s_w[tid][k] = wv[k] * inv;
        s_w[tid][K_DIM] = 0.f;
    }
    __syncthreads();

    // --- bijective XCD swizzle: chunk = NWG/8 = 256 = one batch per XCD ---
    const int bid = blockIdx.x;
    const int swz = (bid & 7) * (NWG / 8) + (bid >> 3);
    const int b   = swz >> 8;           // 0..7
    const int z   = swz & 255;          // 0..255
    const int t0  = z * STRIP;

    const int c = tid * 4;              // block covers all 1024 channels
    const int h = tid >> 4;             // head = c/64

    // head weights -> per-lane VGPRs (8 x ds_read_b128, broadcast in 16-lane groups)
    float w[K_DIM];
    #pragma unroll
    for (int q = 0; q < 8; ++q) {
        const f32x4 t4 = *reinterpret_cast<const f32x4*>(&s_w[h][q * 4]);
        #pragma unroll
        for (int j = 0; j < 4; ++j) {
            if (q * 4 + j < K_DIM) w[q * 4 + j] = t4[j];
        }
    }

    const f32x4 bv = *reinterpret_cast<const f32x4*>(&bias[c]);
    const float* xb = x + (size_t)b * C_DIM + c;
    float* ob = out + (size_t)b * C_DIM + c;

    // interior strips need rows t0-15 .. t0+STRIP-1+15 all in [0, T)
    const bool interior = (t0 >= P_PAD) && (t0 + STRIP - 1 + K_DIM - 1 - P_PAD < T_DIM);
    if (interior) run_strip4<false>(xb, ob, w, bv, t0);
    else          run_strip4<true >(xb, ob, w, bv, t0);
}

extern "C" void kernel_launch(void* const* d_in, const int* in_sizes, int n_in,
                              void* d_out, int out_size, void* d_ws, size_t ws_size,
                              hipStream_t stream) {
    const float* x      = (const float*)d_in[0];
    const float* weight = (const float*)d_in[1];
    const float* bias   = (const float*)d_in[2];
    float* out = (float*)d_out;

    lwconv_tbc_kernel<<<dim3(NWG), dim3(256), 0, stream>>>(x, weight, bias, out);
}

// Round 7
// 31.265 us; speedup vs baseline: 7.8874x; 7.5985x over previous
//
#include <hip/hip_runtime.h>
#include <math.h>

// LightweightConv1dTBC: out[t,b,c] = sum_k x[t-15+k, b, c] * softmax(w[h(c),:])[k] + bias[c]
// T=2048 B=8 C=1024 H=16 K=31 P=15, R = C/H = 64 channels per head.
//
// R6 = R5 structure with the REGISTER BUDGET fixed.
// R4/R5 post-mortem: __launch_bounds__(256,4) left the allocator's occupancy
// target at 8 waves/EU -> 64-VGPR budget -> ~40 regs spilled to scratch
// (FETCH 577MB, VALUBusy 4%). amdgpu_waves_per_eu(2,4) pins the target to
// <=4 waves/EU (128-VGPR budget, relaxable to 256) so the x4 kernel
// (~100 VGPRs live) cannot spill.

#define T_DIM 2048
#define B_DIM 8
#define C_DIM 1024
#define H_DIM 16
#define K_DIM 31
#define P_PAD 15
#define STRIP 8
#define WPAD 32
#define NWG (B_DIM * (T_DIM / STRIP))   // 2048 blocks

typedef float f32x4 __attribute__((ext_vector_type(4)));

template<bool CHECK>
__device__ __forceinline__ void run_strip4(const float* __restrict__ xb,
                                           float* __restrict__ ob,
                                           const float (&w)[K_DIM],
                                           const f32x4 bv, int t0)
{
    f32x4 acc[STRIP];
    #pragma unroll
    for (int i = 0; i < STRIP; ++i) acc[i] = bv;

    #pragma unroll
    for (int r = 0; r < STRIP + K_DIM - 1; ++r) {   // 38 streamed float4 rows
        const int t = t0 - P_PAD + r;
        f32x4 xv = (f32x4)(0.f);
        if (!CHECK || ((unsigned)t < (unsigned)T_DIM)) {
            xv = *reinterpret_cast<const f32x4*>(&xb[(size_t)t * (B_DIM * C_DIM)]);
        }
        #pragma unroll
        for (int i = 0; i < STRIP; ++i) {
            const int k = r - i;
            if (k >= 0 && k < K_DIM) {              // folds statically
                #pragma unroll
                for (int j = 0; j < 4; ++j)
                    acc[i][j] = fmaf(xv[j], w[k], acc[i][j]);
            }
        }
    }

    #pragma unroll
    for (int i = 0; i < STRIP; ++i) {
        __builtin_nontemporal_store(
            acc[i], reinterpret_cast<f32x4*>(&ob[(size_t)(t0 + i) * (B_DIM * C_DIM)]));
    }
}

__global__ __launch_bounds__(256)
__attribute__((amdgpu_waves_per_eu(2, 4)))
void lwconv_tbc_kernel(
    const float* __restrict__ x,       // (T, B, C)
    const float* __restrict__ weight,  // (H, 1, K)
    const float* __restrict__ bias,    // (C,)
    float* __restrict__ out)           // (T, B, C)
{
    __shared__ float s_w[H_DIM][WPAD];  // 2 KB softmaxed weight table

    const int tid = threadIdx.x;

    // --- per-block softmax: threads 0..15 each handle one head (serial, tiny) ---
    if (tid < H_DIM) {
        float wv[K_DIM];
        float m = -1e30f;
        for (int k = 0; k < K_DIM; ++k) {
            wv[k] = weight[tid * K_DIM + k];
            m = fmaxf(m, wv[k]);
        }
        float s = 0.f;
        for (int k = 0; k < K_DIM; ++k) { wv[k] = expf(wv[k] - m); s += wv[k]; }
        const float inv = 1.f / s;
        for (int k = 0; k < K_DIM; ++k) s_w[tid][k] = wv[k] * inv;
        s_w[tid][K_DIM] = 0.f;
    }
    __syncthreads();

    // --- bijective XCD swizzle: chunk = NWG/8 = 256 = one batch per XCD ---
    const int bid = blockIdx.x;
    const int swz = (bid & 7) * (NWG / 8) + (bid >> 3);
    const int b   = swz >> 8;           // 0..7
    const int z   = swz & 255;          // 0..255
    const int t0  = z * STRIP;

    const int c = tid * 4;              // block covers all 1024 channels
    const int h = tid >> 4;             // head = c/64

    // head weights -> per-lane VGPRs (8 x ds_read_b128, 16-lane broadcast groups)
    float w[K_DIM];
    #pragma unroll
    for (int q = 0; q < 8; ++q) {
        const f32x4 t4 = *reinterpret_cast<const f32x4*>(&s_w[h][q * 4]);
        #pragma unroll
        for (int j = 0; j < 4; ++j) {
            if (q * 4 + j < K_DIM) w[q * 4 + j] = t4[j];
        }
    }

    const f32x4 bv = *reinterpret_cast<const f32x4*>(&bias[c]);
    const float* xb = x + (size_t)b * C_DIM + c;
    float* ob = out + (size_t)b * C_DIM + c;

    // interior strips need rows t0-15 .. t0+STRIP-1+15 all in [0, T)
    const bool interior = (t0 >= P_PAD) && (t0 + STRIP - 1 + K_DIM - 1 - P_PAD < T_DIM);
    if (interior) run_strip4<false>(xb, ob, w, bv, t0);
    else          run_strip4<true >(xb, ob, w, bv, t0);
}

extern "C" void kernel_launch(void* const* d_in, const int* in_sizes, int n_in,
                              void* d_out, int out_size, void* d_ws, size_t ws_size,
                              hipStream_t stream) {
    const float* x      = (const float*)d_in[0];
    const float* weight = (const float*)d_in[1];
    const float* bias   = (const float*)d_in[2];
    float* out = (float*)d_out;

    lwconv_tbc_kernel<<<dim3(NWG), dim3(256), 0, stream>>>(x, weight, bias, out);
}